// Round 1
// baseline (173.041 us; speedup 1.0000x reference)
//
#include <hip/hip_runtime.h>
#include <hip/hip_bf16.h>

#define NE 32
#define MM 1024
#define KK 512
#define NN 512
#define BM 128
#define BN 128
#define BK 32
#define LDST (BK + 8)   // bf16 elements per LDS row (+8 pad -> 80B stride, b128-friendly)

typedef __attribute__((ext_vector_type(8))) short bf16x8;
typedef __attribute__((ext_vector_type(4))) short shortx4;
typedef __attribute__((ext_vector_type(4))) float floatx4;

__device__ __forceinline__ short f2bf(float f) {
  union { __hip_bfloat16 b; short s; } u;
  u.b = __float2bfloat16(f);   // RNE — unbiased over K=512 accumulation
  return u.s;
}

extern "C" __global__ __launch_bounds__(256, 2)
void expert_gemm(const float* __restrict__ A, const float* __restrict__ B,
                 const int* __restrict__ cnts, float* __restrict__ C)
{
  const int bid = blockIdx.x;
  const int e   = bid >> 5;        // 32 tiles per expert (8 mt x 4 nt)
  const int rem = bid & 31;
  const int mt  = rem >> 2;
  const int nt  = rem & 3;
  const int m0  = mt * BM;
  const int n0  = nt * BN;
  const int cnt = cnts[e];
  const int tid = threadIdx.x;

  float* Ce = C + ((size_t)e * MM + m0) * NN + n0;

  // Fast path: whole tile above the valid-row watermark -> pure zero-fill.
  // (harness re-poisons d_out to 0xAA before every launch; we must write zeros)
  if (m0 >= cnt) {
    float4 z = make_float4(0.f, 0.f, 0.f, 0.f);
#pragma unroll
    for (int i = 0; i < 16; ++i) {
      int idx = i * 256 + tid;     // float4 index within 128x128 tile
      int r = idx >> 5;            // 32 float4 per row
      int c = (idx & 31) << 2;
      *(float4*)(Ce + (size_t)r * NN + c) = z;
    }
    return;
  }

  const float* Ae = A + ((size_t)e * MM + m0) * KK;
  const float* Be = B + ((size_t)e * NN + n0) * KK;

  __shared__ __align__(16) short lA[BM * LDST];
  __shared__ __align__(16) short lB[BN * LDST];

  const int wave = tid >> 6;
  const int lane = tid & 63;
  const int wm = (wave >> 1) * 64;  // wave's 64x64 subtile origin
  const int wn = (wave & 1) * 64;
  const int fr = lane & 15;         // fragment row (m or n within 16)
  const int kh = lane >> 4;         // k-half selector: k = kh*8 + j

  // staging map: thread t -> row = t>>3 (+32 per pass), 4 consecutive floats
  const int srow = tid >> 3;
  const int scol = (tid & 7) << 2;

  floatx4 acc[4][4] = {};

  // prefetch K-slab 0 into registers
  float4 ra[4], rbv[4];
#pragma unroll
  for (int p = 0; p < 4; ++p) {
    ra[p]  = *(const float4*)(Ae + (size_t)(srow + p * 32) * KK + scol);
    rbv[p] = *(const float4*)(Be + (size_t)(srow + p * 32) * KK + scol);
  }

  for (int kt = 0; kt < KK; kt += BK) {
    __syncthreads();   // previous iter's ds_reads done before overwrite
#pragma unroll
    for (int p = 0; p < 4; ++p) {
      shortx4 va = { f2bf(ra[p].x),  f2bf(ra[p].y),  f2bf(ra[p].z),  f2bf(ra[p].w)  };
      shortx4 vb = { f2bf(rbv[p].x), f2bf(rbv[p].y), f2bf(rbv[p].z), f2bf(rbv[p].w) };
      *(shortx4*)(lA + (srow + p * 32) * LDST + scol) = va;
      *(shortx4*)(lB + (srow + p * 32) * LDST + scol) = vb;
    }
    __syncthreads();

    // prefetch next K-slab while this one computes
    if (kt + BK < KK) {
#pragma unroll
      for (int p = 0; p < 4; ++p) {
        ra[p]  = *(const float4*)(Ae + (size_t)(srow + p * 32) * KK + kt + BK + scol);
        rbv[p] = *(const float4*)(Be + (size_t)(srow + p * 32) * KK + kt + BK + scol);
      }
    }

    // LDS -> fragments (ds_read_b128), then 16 MFMAs
    bf16x8 af[4], bfv[4];
#pragma unroll
    for (int i = 0; i < 4; ++i) {
      af[i]  = *(bf16x8*)(lA + (wm + i * 16 + fr) * LDST + kh * 8);
      bfv[i] = *(bf16x8*)(lB + (wn + i * 16 + fr) * LDST + kh * 8);
    }
#pragma unroll
    for (int i = 0; i < 4; ++i)
#pragma unroll
      for (int j = 0; j < 4; ++j)
        acc[i][j] = __builtin_amdgcn_mfma_f32_16x16x32_bf16(af[i], bfv[j], acc[i][j], 0, 0, 0);
  }

  // epilogue: C/D layout col=lane&15, row=(lane>>4)*4+reg (m89/m91-verified)
  const int rb_ = (lane >> 4) * 4;
#pragma unroll
  for (int i = 0; i < 4; ++i) {
#pragma unroll
    for (int r = 0; r < 4; ++r) {
      int row = wm + i * 16 + rb_ + r;
      bool valid = (m0 + row) < cnt;
#pragma unroll
      for (int j = 0; j < 4; ++j) {
        int col = wn + j * 16 + fr;
        Ce[(size_t)row * NN + col] = valid ? acc[i][j][r] : 0.0f;
      }
    }
  }
}

extern "C" void kernel_launch(void* const* d_in, const int* in_sizes, int n_in,
                              void* d_out, int out_size, void* d_ws, size_t ws_size,
                              hipStream_t stream) {
  const float* A    = (const float*)d_in[0];
  const float* B    = (const float*)d_in[1];
  const int*   cnts = (const int*)d_in[2];
  float*       C    = (float*)d_out;

  dim3 grid(NE * (MM / BM) * (NN / BN));   // 32 * 8 * 4 = 1024 blocks
  dim3 block(256);
  hipLaunchKernelGGL(expert_gemm, grid, block, 0, stream, A, B, cnts, C);
}